// Round 1
// baseline (270.818 us; speedup 1.0000x reference)
//
#include <hip/hip_runtime.h>
#include <cmath>
#include <cfloat>

constexpr int D  = 128;
constexpr int NT = 256;            // threads per block (4 waves)
constexpr float GAMMA_ = 0.1f;
constexpr float EPS_   = 1e-10f;

__global__ __launch_bounds__(NT) void adaptive_sampler_kernel(
    const float* __restrict__ target,   // [B, D]
    const float* __restrict__ cand,     // [B, N, D]
    const float* __restrict__ Wq,       // [D, D]
    const float* __restrict__ bq,       // [D]
    const float* __restrict__ Wk,       // [D, D]
    const float* __restrict__ u,        // [B, N]
    const int*   __restrict__ kptr,     // scalar: num_neighbors
    int*         __restrict__ out,      // [B, k]
    int N)
{
  extern __shared__ float sS[];         // N floats: scores, then values
  __shared__ float sTgt[D];
  __shared__ float sQ[D];
  __shared__ float sQt[D];
  __shared__ float redV[NT / 64];
  __shared__ int   redI[NT / 64];

  const int b    = blockIdx.x;
  const int tid  = threadIdx.x;
  const int lane = tid & 63;
  const int wave = tid >> 6;

  // ---- stage target row ----
  if (tid < D) sTgt[tid] = target[(size_t)b * D + tid];
  __syncthreads();

  // ---- Q[d] = bq[d] + sum_e tgt[e] * Wq[d,e] ----
  if (tid < D) {
    float acc = 0.f;
    const float* wrow = Wq + (size_t)tid * D;
    #pragma unroll 8
    for (int e = 0; e < D; ++e) acc += sTgt[e] * wrow[e];
    sQ[tid] = acc + bq[tid];
  }
  __syncthreads();

  // ---- qt[e] = sum_d Q[d] * Wk[d,e]   (q~ = Wk^T Q) ----
  if (tid < D) {
    float acc = 0.f;
    #pragma unroll 8
    for (int d = 0; d < D; ++d) acc += sQ[d] * Wk[(size_t)d * D + tid];
    sQt[tid] = acc;
  }
  __syncthreads();

  // ---- scores: 16 lanes per row; each lane owns 8 contiguous d's ----
  const int grp = lane >> 4;            // 0..3 (row group within wave)
  const int gl  = lane & 15;            // 0..15 (position within row)
  // hoist this lane's 8 q~ values to registers (no LDS in hot loop)
  float q0 = sQt[gl * 8 + 0], q1 = sQt[gl * 8 + 1];
  float q2 = sQt[gl * 8 + 2], q3 = sQt[gl * 8 + 3];
  float q4 = sQt[gl * 8 + 4], q5 = sQt[gl * 8 + 5];
  float q6 = sQt[gl * 8 + 6], q7 = sQt[gl * 8 + 7];

  const float scale = sqrtf((float)D);

  for (int n = wave * 4 + grp; n < N; n += 16) {
    const float4* row = (const float4*)(cand + ((size_t)b * N + n) * D);
    float4 a0 = row[gl * 2 + 0];
    float4 a1 = row[gl * 2 + 1];
    float p = a0.x * q0 + a0.y * q1 + a0.z * q2 + a0.w * q3
            + a1.x * q4 + a1.y * q5 + a1.z * q6 + a1.w * q7;
    // reduce across the 16-lane group
    p += __shfl_xor(p, 1);
    p += __shfl_xor(p, 2);
    p += __shfl_xor(p, 4);
    p += __shfl_xor(p, 8);
    if (gl == 0) sS[n] = p / scale;
  }
  __syncthreads();

  // ---- row max ----
  float m = -FLT_MAX;
  for (int n = tid; n < N; n += NT) m = fmaxf(m, sS[n]);
  for (int s = 32; s; s >>= 1) m = fmaxf(m, __shfl_xor(m, s));
  if (lane == 0) redV[wave] = m;
  __syncthreads();
  m = fmaxf(fmaxf(redV[0], redV[1]), fmaxf(redV[2], redV[3]));
  __syncthreads();

  // ---- sum of exp ----
  float ssum = 0.f;
  for (int n = tid; n < N; n += NT) ssum += expf(sS[n] - m);
  for (int s = 32; s; s >>= 1) ssum += __shfl_xor(ssum, s);
  if (lane == 0) redV[wave] = ssum;
  __syncthreads();
  const float Z = redV[0] + redV[1] + redV[2] + redV[3];
  __syncthreads();

  // ---- values: log((1-g)*softmax + g/N) + gumbel ----
  const float mixc = (float)(0.1 / (double)N);   // match double 0.1/N -> f32
  for (int n = tid; n < N; n += NT) {
    float pmix = 0.9f * (expf(sS[n] - m) / Z) + mixc;
    float uv = u[(size_t)b * N + n];
    float g = -logf(-logf(uv + EPS_) + EPS_);
    sS[n] = logf(pmix) + g;
  }
  __syncthreads();

  // ---- top-k by iterative argmax (descending, lower index wins ties) ----
  const int k = kptr[0];
  for (int i = 0; i < k; ++i) {
    float bv = -FLT_MAX;
    int   bi = N;
    for (int n = tid; n < N; n += NT) {
      float v = sS[n];
      if (v > bv || (v == bv && n < bi)) { bv = v; bi = n; }
    }
    for (int s = 32; s; s >>= 1) {
      float ov = __shfl_xor(bv, s);
      int   oi = __shfl_xor(bi, s);
      if (ov > bv || (ov == bv && oi < bi)) { bv = ov; bi = oi; }
    }
    if (lane == 0) { redV[wave] = bv; redI[wave] = bi; }
    __syncthreads();
    if (tid == 0) {
      float fv = redV[0]; int fi = redI[0];
      #pragma unroll
      for (int w = 1; w < NT / 64; ++w) {
        if (redV[w] > fv || (redV[w] == fv && redI[w] < fi)) {
          fv = redV[w]; fi = redI[w];
        }
      }
      out[(size_t)b * k + i] = fi;
      sS[fi] = -FLT_MAX;   // remove from next round
    }
    __syncthreads();
  }
}

extern "C" void kernel_launch(void* const* d_in, const int* in_sizes, int n_in,
                              void* d_out, int out_size, void* d_ws, size_t ws_size,
                              hipStream_t stream) {
  const float* target = (const float*)d_in[0];
  const float* cand   = (const float*)d_in[1];
  const float* Wq     = (const float*)d_in[2];
  const float* bq     = (const float*)d_in[3];
  const float* Wk     = (const float*)d_in[4];
  const float* bk     = (const float*)d_in[5];
  const float* u      = (const float*)d_in[6];
  const int*   kptr   = (const int*)d_in[7];
  (void)bk;  // per-row constant shift: cancels in softmax
  (void)n_in; (void)d_ws; (void)ws_size; (void)out_size;

  const int B = in_sizes[0] / D;
  const int N = in_sizes[1] / (B * D);

  adaptive_sampler_kernel<<<B, NT, N * sizeof(float), stream>>>(
      target, cand, Wq, bq, Wk, u, kptr, (int*)d_out, N);
}

// Round 2
// 256.587 us; speedup vs baseline: 1.0555x; 1.0555x over previous
//
#include <hip/hip_runtime.h>
#include <cmath>
#include <cfloat>

constexpr int D  = 128;
constexpr int NT = 512;            // threads per block (8 waves)
constexpr int NW = NT / 64;        // waves per block
constexpr float EPS_ = 1e-10f;

__global__ __launch_bounds__(NT, 8) void adaptive_sampler_kernel(
    const float* __restrict__ target,   // [B, D]
    const float* __restrict__ cand,     // [B, N, D]
    const float* __restrict__ Wq,       // [D, D]
    const float* __restrict__ bq,       // [D]
    const float* __restrict__ Wk,       // [D, D]
    const float* __restrict__ u,        // [B, N]
    const int*   __restrict__ kptr,     // scalar: num_neighbors
    int*         __restrict__ out,      // [B, k]
    int N)
{
  extern __shared__ float sS[];         // N floats: scores, then values
  __shared__ float sTgt[D];
  __shared__ float sQ[D];
  __shared__ float sQt[D];
  __shared__ float redV[NW];
  __shared__ int   redI[NW];

  const int b    = blockIdx.x;
  const int tid  = threadIdx.x;
  const int lane = tid & 63;
  const int wave = tid >> 6;

  // ---- stage target row ----
  if (tid < D) sTgt[tid] = target[(size_t)b * D + tid];
  __syncthreads();

  // ---- Q[d] = bq[d] + sum_e tgt[e] * Wq[d,e] ----
  if (tid < D) {
    float acc = 0.f;
    const float* wrow = Wq + (size_t)tid * D;
    #pragma unroll 8
    for (int e = 0; e < D; ++e) acc += sTgt[e] * wrow[e];
    sQ[tid] = acc + bq[tid];
  }
  __syncthreads();

  // ---- qt[e] = sum_d Q[d] * Wk[d,e]   (q~ = Wk^T Q) ----
  if (tid < D) {
    float acc = 0.f;
    #pragma unroll 8
    for (int d = 0; d < D; ++d) acc += sQ[d] * Wk[(size_t)d * D + tid];
    sQt[tid] = acc;
  }
  __syncthreads();

  // ---- scores: 16 lanes per row; each lane owns 8 contiguous d's ----
  const int grp = lane >> 4;            // 0..3 (row group within wave)
  const int gl  = lane & 15;            // 0..15 (position within row)
  float q0 = sQt[gl * 8 + 0], q1 = sQt[gl * 8 + 1];
  float q2 = sQt[gl * 8 + 2], q3 = sQt[gl * 8 + 3];
  float q4 = sQt[gl * 8 + 4], q5 = sQt[gl * 8 + 5];
  float q6 = sQt[gl * 8 + 6], q7 = sQt[gl * 8 + 7];

  const float scale = sqrtf((float)D);
  const int rstride = NW * 4;           // rows per block-sweep (32)

  int n = wave * 4 + grp;
  for (; n + rstride < N; n += 2 * rstride) {
    // issue 4 independent float4 loads (two rows) before any reduce
    const float4* r0 = (const float4*)(cand + ((size_t)b * N + n) * D);
    const float4* r1 = (const float4*)(cand + ((size_t)b * N + n + rstride) * D);
    float4 a0 = r0[gl * 2 + 0];
    float4 a1 = r0[gl * 2 + 1];
    float4 c0 = r1[gl * 2 + 0];
    float4 c1 = r1[gl * 2 + 1];
    float p0 = a0.x * q0 + a0.y * q1 + a0.z * q2 + a0.w * q3
             + a1.x * q4 + a1.y * q5 + a1.z * q6 + a1.w * q7;
    float p1 = c0.x * q0 + c0.y * q1 + c0.z * q2 + c0.w * q3
             + c1.x * q4 + c1.y * q5 + c1.z * q6 + c1.w * q7;
    // two independent interleaved reduce chains
    p0 += __shfl_xor(p0, 1);  p1 += __shfl_xor(p1, 1);
    p0 += __shfl_xor(p0, 2);  p1 += __shfl_xor(p1, 2);
    p0 += __shfl_xor(p0, 4);  p1 += __shfl_xor(p1, 4);
    p0 += __shfl_xor(p0, 8);  p1 += __shfl_xor(p1, 8);
    if (gl == 0) { sS[n] = p0 / scale; sS[n + rstride] = p1 / scale; }
  }
  if (n < N) {
    const float4* r0 = (const float4*)(cand + ((size_t)b * N + n) * D);
    float4 a0 = r0[gl * 2 + 0];
    float4 a1 = r0[gl * 2 + 1];
    float p0 = a0.x * q0 + a0.y * q1 + a0.z * q2 + a0.w * q3
             + a1.x * q4 + a1.y * q5 + a1.z * q6 + a1.w * q7;
    p0 += __shfl_xor(p0, 1);
    p0 += __shfl_xor(p0, 2);
    p0 += __shfl_xor(p0, 4);
    p0 += __shfl_xor(p0, 8);
    if (gl == 0) sS[n] = p0 / scale;
  }
  __syncthreads();

  // ---- row max ----
  float m = -FLT_MAX;
  for (int i = tid; i < N; i += NT) m = fmaxf(m, sS[i]);
  for (int s = 32; s; s >>= 1) m = fmaxf(m, __shfl_xor(m, s));
  if (lane == 0) redV[wave] = m;
  __syncthreads();
  m = redV[0];
  #pragma unroll
  for (int w = 1; w < NW; ++w) m = fmaxf(m, redV[w]);
  __syncthreads();

  // ---- sum of exp ----
  float ssum = 0.f;
  for (int i = tid; i < N; i += NT) ssum += expf(sS[i] - m);
  for (int s = 32; s; s >>= 1) ssum += __shfl_xor(ssum, s);
  if (lane == 0) redV[wave] = ssum;
  __syncthreads();
  float Z = redV[0];
  #pragma unroll
  for (int w = 1; w < NW; ++w) Z += redV[w];
  __syncthreads();

  // ---- values: log((1-g)*softmax + g/N) + gumbel ----
  const float mixc = (float)(0.1 / (double)N);
  for (int i = tid; i < N; i += NT) {
    float pmix = 0.9f * (expf(sS[i] - m) / Z) + mixc;
    float uv = u[(size_t)b * N + i];
    float g = -logf(-logf(uv + EPS_) + EPS_);
    sS[i] = logf(pmix) + g;
  }
  __syncthreads();

  // ---- top-k by iterative argmax (descending, lower index wins ties) ----
  const int k = kptr[0];
  for (int i = 0; i < k; ++i) {
    float bv = -FLT_MAX;
    int   bi = N;
    for (int j = tid; j < N; j += NT) {
      float v = sS[j];
      if (v > bv || (v == bv && j < bi)) { bv = v; bi = j; }
    }
    for (int s = 32; s; s >>= 1) {
      float ov = __shfl_xor(bv, s);
      int   oi = __shfl_xor(bi, s);
      if (ov > bv || (ov == bv && oi < bi)) { bv = ov; bi = oi; }
    }
    if (lane == 0) { redV[wave] = bv; redI[wave] = bi; }
    __syncthreads();
    if (tid == 0) {
      float fv = redV[0]; int fi = redI[0];
      #pragma unroll
      for (int w = 1; w < NW; ++w) {
        if (redV[w] > fv || (redV[w] == fv && redI[w] < fi)) {
          fv = redV[w]; fi = redI[w];
        }
      }
      out[(size_t)b * k + i] = fi;
      sS[fi] = -FLT_MAX;   // remove from next round
    }
    __syncthreads();
  }
}

extern "C" void kernel_launch(void* const* d_in, const int* in_sizes, int n_in,
                              void* d_out, int out_size, void* d_ws, size_t ws_size,
                              hipStream_t stream) {
  const float* target = (const float*)d_in[0];
  const float* cand   = (const float*)d_in[1];
  const float* Wq     = (const float*)d_in[2];
  const float* bq     = (const float*)d_in[3];
  const float* Wk     = (const float*)d_in[4];
  const float* bk     = (const float*)d_in[5];
  const float* u      = (const float*)d_in[6];
  const int*   kptr   = (const int*)d_in[7];
  (void)bk;  // per-row constant shift: cancels in softmax
  (void)n_in; (void)d_ws; (void)ws_size; (void)out_size;

  const int B = in_sizes[0] / D;
  const int N = in_sizes[1] / (B * D);

  adaptive_sampler_kernel<<<B, NT, N * sizeof(float), stream>>>(
      target, cand, Wq, bq, Wk, u, kptr, (int*)d_out, N);
}